// Round 22
// baseline (5074.667 us; speedup 1.0000x reference)
//
#include <hip/hip_runtime.h>
#include <hip/hip_bf16.h>

// Problem sizes
#define Bb 128
#define Tt 1024
#define Dd 256
#define Hh 512
#define G4 2048
#define Oo 256

#define NBG 8        // batch groups (16 rows each), one per XCD by construction
#define WPB 8        // worker wgs per batch group (64 h-cols each)
#define NWG_LAUNCH 128  // launch 2x needed; surplus wgs exit after ticket claim
#define BLOCK 512    // 8 waves

#define SPIN_CAP (1u << 16)   // PER-STEP spin cap (with s_sleep backoff)

typedef __attribute__((ext_vector_type(8))) short short8;
typedef __attribute__((ext_vector_type(4))) float f32x4;
typedef unsigned long long u64;

// ws layout: [tickets: 8 x 64B @0][cnt: 8 x 128B @2048][hbuf: 2*128*512 bf16 @4096]
#define TICK_OFF 0
#define CNT_OFF  2048
#define HBUF_OFF 4096
#define WS_ZERO_BYTES (4096 + Bb*Hh*2)   // tickets + counters + hbuf half 0

__device__ __forceinline__ short f2bf(float f) {
  __hip_bfloat16 h = __float2bfloat16(f);
  return *reinterpret_cast<short*>(&h);
}
__device__ __forceinline__ float sigm(float x) {
  return __builtin_amdgcn_rcpf(1.f + __expf(-x));
}
__device__ __forceinline__ float tanh_(float x) {
  return fmaf(2.f, __builtin_amdgcn_rcpf(1.f + __expf(-2.f * x)), -1.f);
}

#define MFMA16(A, B, C) __builtin_amdgcn_mfma_f32_16x16x32_bf16((A), (B), (C), 0, 0, 0)

__global__ __launch_bounds__(BLOCK, 2) void lstm_seq(
    const float* __restrict__ X, const float* __restrict__ Wi,
    const float* __restrict__ Wh, const float* __restrict__ bias,
    char* hbuf, int* cnts, int* tickets)
{
  __shared__ char sH[16 * 1024];            // h tile (bf16, XOR-swizzled)
  __shared__ char sX[16 * 512];             // x tile (bf16, XOR-swizzled)
  __shared__ unsigned short hstage[16][72]; // wg h-slice (16 rows x 64 cols), padded
  __shared__ int sSlot;

  const int tid  = threadIdx.x;
  const int w    = tid >> 6;      // wave 0..7
  const int lane = tid & 63;

  // ---- Role claim: all 8 workers of a bg are on XCD bg BY CONSTRUCTION.
  int myxcc;
  asm volatile("s_getreg_b32 %0, hwreg(HW_REG_XCC_ID)" : "=s"(myxcc));
  myxcc &= 7;
  if (tid == 0) {
    sSlot = __hip_atomic_fetch_add(&tickets[myxcc * 16], 1,
                                   __ATOMIC_RELAXED, __HIP_MEMORY_SCOPE_AGENT);
  }
  __syncthreads();
  const int gjw = sSlot;          // col-group: h-cols [gjw*64, +64)
  if (gjw >= WPB) return;         // surplus wg: exit (wg-uniform)
  const int bg = myxcc;           // batch group == this XCD
  int* cnt = cnts + bg * 32;      // 128B apart per bg

  // ---- Persistent weight B-fragments: TWO n-tiles per wave (wf[2][24]).
  // nt0 covers gates i (cjj<8), f (cjj>=8); nt1 covers g, o.
  // Lane col: c = nt*16 + cjj; gate = c>>3; jj0 = c&7;
  // colg = gate*Hh + gjw*64 + w*8 + jj0.
  // B lane map (16x16x32): col = lane&15, k = kk*32 + (lane>>4)*8 + i
  const int cjj  = lane & 15;
  const int kgrp = lane >> 4;        // 0..3
  short8 wf[2][24];
  float bv[2];
#pragma unroll
  for (int nt = 0; nt < 2; ++nt) {
    int c = nt * 16 + cjj;
    int gate = c >> 3, jj0 = c & 7;
    int colg = gate * Hh + gjw * 64 + w * 8 + jj0;
    bv[nt] = bias[colg];
#pragma unroll
    for (int kk = 0; kk < 24; ++kk) {
      short8 f;
#pragma unroll
      for (int i = 0; i < 8; ++i) {
        int k = kk * 32 + kgrp * 8 + i;
        float v = (k < Hh) ? Wh[(size_t)k * G4 + colg]
                           : Wi[(size_t)(k - Hh) * G4 + colg];
        f[i] = f2bf(v);
      }
      wf[nt][kk] = f;
    }
  }

  const int arow = cjj;              // MFMA A row
  const int aswz = (arow & 7) << 4;
  const int ejj  = cjj & 7;          // epilogue col-within-8 (productive: cjj<8)
  float cpr[4] = {0.f, 0.f, 0.f, 0.f};  // c-state rows kgrp*4+m (cjj<8 lanes)

  // ---- h-staging mapping, STAGGERED by gjw (8 wgs sweep at different rows)
  const int hc0 = (tid + gjw * 128) & 1023;
  const int hc1 = (tid + 512 + gjw * 128) & 1023;
  const int hrow0 = hc0 >> 6, hoff0 = hc0 & 63;
  const int hrow1 = hc1 >> 6, hoff1 = hc1 & 63;

  // ---- x prefetch (2-step pipeline in registers)
  const int xrow = tid >> 5, xseg = tid & 31;   // wg covers 16 rows x 256 f32
  const float* xbase = X + (size_t)(bg * 16 + xrow) * Tt * Dd + xseg * 8;
  f32x4 xA0 = *reinterpret_cast<const f32x4*>(xbase);
  f32x4 xA1 = *reinterpret_cast<const f32x4*>(xbase + 4);
  f32x4 xB0 = *reinterpret_cast<const f32x4*>(xbase + Dd);
  f32x4 xB1 = *reinterpret_cast<const f32x4*>(xbase + Dd + 4);

  auto STEP = [&](int s, f32x4& xv0, f32x4& xv1) {
    const char* hread  = hbuf + (size_t)((s - 1) & 1) * (Bb * Hh * 2);
    char*       hwrite = hbuf + (size_t)(s & 1) * (Bb * Hh * 2);

    // ---- 1. stage x_t into sX from regs prefetched 2 steps ago
    {
      short8 xb;
      xb[0] = f2bf(xv0[0]); xb[1] = f2bf(xv0[1]); xb[2] = f2bf(xv0[2]); xb[3] = f2bf(xv0[3]);
      xb[4] = f2bf(xv1[0]); xb[5] = f2bf(xv1[1]); xb[6] = f2bf(xv1[2]); xb[7] = f2bf(xv1[3]);
      *reinterpret_cast<short8*>(sX + xrow * 512 + ((xseg * 16) ^ ((xrow & 7) << 4))) = xb;
    }
    __syncthreads();   // sX handoff

    // ---- 2. x-part MFMA (k = 512..767), 2 n-tiles x 2 chains — overlaps poll
    f32x4 a0a, a0b, a1a, a1b;
#pragma unroll
    for (int m = 0; m < 4; ++m) {
      a0a[m] = bv[0]; a0b[m] = 0.f; a1a[m] = bv[1]; a1b[m] = 0.f;
    }
#pragma unroll
    for (int kk = 0; kk < 4; ++kk) {
      short8 a = *reinterpret_cast<const short8*>(
          sX + arow * 512 + ((kk * 64 + kgrp * 16) ^ aswz));
      a0a = MFMA16(a, wf[0][16 + kk], a0a);
      a1a = MFMA16(a, wf[1][16 + kk], a1a);
    }
#pragma unroll
    for (int kk = 4; kk < 8; ++kk) {
      short8 a = *reinterpret_cast<const short8*>(
          sX + arow * 512 + ((kk * 64 + kgrp * 16) ^ aswz));
      a0b = MFMA16(a, wf[0][16 + kk], a0b);
      a1b = MFMA16(a, wf[1][16 + kk], a1b);
    }

    // ---- 3. wait for the 8 producers of this bg (step s-1). Non-idempotent
    // RMW at the XCD L2 atomic point (proven coherent; R18: load-polls are
    // not). s_sleep backoff keeps the flag line free. PER-STEP spin cap.
    if (s > 1 && tid == 0) {
      const int tgt = WPB * (s - 1);
      unsigned spin = 0;
      while ((int)(__hip_atomic_fetch_add((unsigned*)cnt, 0x10000u,
                                          __ATOMIC_RELAXED,
                                          __HIP_MEMORY_SCOPE_WORKGROUP) & 0xFFFFu) < tgt
             && ++spin < SPIN_CAP) {
        __builtin_amdgcn_s_sleep(1);
      }
    }
    __syncthreads();

    // ---- 4. invalidate L1, cooperative coalesced h(s-1) staging (staggered):
    // 16KB from XCD L2 via plain cached loads.
    asm volatile("buffer_inv sc0" ::: "memory");
    {
      f32x4 v0 = *reinterpret_cast<const f32x4*>(
          hread + (size_t)(bg * 16 + hrow0) * 1024 + hoff0 * 16);
      f32x4 v1 = *reinterpret_cast<const f32x4*>(
          hread + (size_t)(bg * 16 + hrow1) * 1024 + hoff1 * 16);
      *reinterpret_cast<f32x4*>(
          sH + hrow0 * 1024 + ((hoff0 * 16) ^ ((hrow0 & 7) << 4))) = v0;
      *reinterpret_cast<f32x4*>(
          sH + hrow1 * 1024 + ((hoff1 * 16) ^ ((hrow1 & 7) << 4))) = v1;
    }
    __syncthreads();

    // ---- 5. h-part MFMA (k = 0..511), 2 n-tiles x 2 chains
#pragma unroll
    for (int kk = 0; kk < 8; ++kk) {
      short8 a = *reinterpret_cast<const short8*>(
          sH + arow * 1024 + ((kk * 64 + kgrp * 16) ^ aswz));
      a0a = MFMA16(a, wf[0][kk], a0a);
      a1a = MFMA16(a, wf[1][kk], a1a);
    }
#pragma unroll
    for (int kk = 8; kk < 16; ++kk) {
      short8 a = *reinterpret_cast<const short8*>(
          sH + arow * 1024 + ((kk * 64 + kgrp * 16) ^ aswz));
      a0b = MFMA16(a, wf[0][kk], a0b);
      a1b = MFMA16(a, wf[1][kk], a1b);
    }
    f32x4 acc0, acc1;
#pragma unroll
    for (int m = 0; m < 4; ++m) {
      acc0[m] = a0a[m] + a0b[m];
      acc1[m] = a1a[m] + a1b[m];
    }

    // ---- 6. gate gather: one shfl_xor(8) round swaps i<->f (acc0) and
    // g<->o (acc1) between lane pairs. Lanes cjj<8 (32/wave) compute gates
    // for rows kgrp*4+m, col w*8+ejj.
    float o0[4], o1[4];
#pragma unroll
    for (int m = 0; m < 4; ++m) {
      o0[m] = __shfl_xor(acc0[m], 8);
      o1[m] = __shfl_xor(acc1[m], 8);
    }
    if (cjj < 8) {
#pragma unroll
      for (int m = 0; m < 4; ++m) {
        float ig = sigm(acc0[m]), fg = sigm(o0[m]);
        float gg = tanh_(acc1[m]), og = sigm(o1[m]);
        float c = fg * cpr[m] + ig * gg;
        cpr[m] = c;
        float hh = og * tanh_(c);
        __hip_bfloat16 hb = __float2bfloat16(hh);
        hstage[kgrp * 4 + m][w * 8 + ejj] = *reinterpret_cast<unsigned short*>(&hb);
      }
    }
    __syncthreads();

    // ---- 7. store h slice (wave 0 only: 64 threads x 32B, coalesced;
    // write-through L1 -> shared XCD L2), wave-local drain, signal.
    if (tid < 64) {
      int row = tid >> 2, cp = tid & 3;   // cp: 32B pair within 128B row
      const char* src = reinterpret_cast<const char*>(&hstage[row][0]) + cp * 32;
      f32x4 v0 = *reinterpret_cast<const f32x4*>(src);
      f32x4 v1 = *reinterpret_cast<const f32x4*>(src + 16);
      char* dst = hwrite + ((size_t)(bg * 16 + row) * Hh + gjw * 64 + cp * 16) * 2;
      *reinterpret_cast<f32x4*>(dst) = v0;
      *reinterpret_cast<f32x4*>(dst + 16) = v1;
      asm volatile("s_waitcnt vmcnt(0)" ::: "memory");  // wave-0 stores at L2
      if (tid == 0) {
        (void)__hip_atomic_fetch_add(cnt, 1, __ATOMIC_RELAXED,
                                     __HIP_MEMORY_SCOPE_WORKGROUP);
      }
    }

    // ---- 8. refill x for step s+2 (latency hidden under the next step)
    if (s + 2 <= Tt) {
      xv0 = *reinterpret_cast<const f32x4*>(xbase + (size_t)(s + 1) * Dd);
      xv1 = *reinterpret_cast<const f32x4*>(xbase + (size_t)(s + 1) * Dd + 4);
    }
  };

  for (int s = 1; s <= Tt; s += 2) {
    STEP(s,     xA0, xA1);
    STEP(s + 1, xB0, xB1);
  }
}

__global__ void out_dense(const __hip_bfloat16* __restrict__ hT,
                          const float* __restrict__ Wd,
                          const float* __restrict__ bd,
                          float* __restrict__ out)
{
  // lstm_seq's end-of-kernel release writes dirty L2 back; plain loads ok.
  __shared__ float hrow[Hh];
  int b = blockIdx.x;
  int o = threadIdx.x;
  for (int k = o; k < Hh; k += Oo)
    hrow[k] = __bfloat162float(hT[(size_t)b * Hh + k]);
  __syncthreads();
  float acc = bd[o];
  for (int k = 0; k < Hh; ++k)
    acc = fmaf(hrow[k], Wd[(size_t)k * Oo + o], acc);
  out[(size_t)b * Oo + o] = acc;
}

extern "C" void kernel_launch(void* const* d_in, const int* in_sizes, int n_in,
                              void* d_out, int out_size, void* d_ws, size_t ws_size,
                              hipStream_t stream) {
  (void)in_sizes; (void)n_in; (void)out_size; (void)ws_size;
  const float* X  = (const float*)d_in[0];
  const float* Wi = (const float*)d_in[1];
  const float* Wh = (const float*)d_in[2];
  const float* b  = (const float*)d_in[3];
  const float* Wd = (const float*)d_in[4];
  const float* bd = (const float*)d_in[5];
  float* out = (float*)d_out;

  char* ws = (char*)d_ws;
  int* tickets = (int*)(ws + TICK_OFF);
  int* cnts    = (int*)(ws + CNT_OFF);
  char* hbuf   = ws + HBUF_OFF;

  // zero tickets, counters, and h(0) every launch (graph-replay deterministic)
  hipMemsetAsync(d_ws, 0, WS_ZERO_BYTES, stream);
  lstm_seq<<<NWG_LAUNCH, BLOCK, 0, stream>>>(X, Wi, Wh, b, hbuf, cnts, tickets);
  out_dense<<<Bb, Oo, 0, stream>>>((const __hip_bfloat16*)hbuf, Wd, bd, out);
}